// Round 7
// baseline (14083.736 us; speedup 1.0000x reference)
//
#include <hip/hip_runtime.h>

// ============================================================================
// AttnDecoderRNN round 12: make the per-XCD working set L2-RESIDENT.
// R11 post-mortem: 32 MB/step refetched from L3 at 1.08 TB/s = the 30us step.
// Per-XCD footprint was 7.8 MB > 4 MiB L2.  R12 partitions BY OUTPUT COLUMN
// across XCDs so each XCD only ever touches:
//   wcat slice 327 KB + keys(8 batches, bf16) 2.1 MB + enc8 1.05 MB +
//   Wih slice 196 KB  ~= 3.7 MB  < 4 MiB  -> resident across steps.
// encpt (25 MB) deleted; gi = Wih.ctx GEMM (R5-proven numerics).
// Grid: 64 blocks x 512.  x=bid&7 (XCD), p=bid>>3.
//   A (p<4, 32 blk): [q|gh+bhh|logits+bout] = h @ Wcat^T, 5 col-tiles/blk,
//     XCD x owns cols [320x..320x+320) -> wcat slice L2-resident.
//   B (all 64, block b=bid): full attention for batch b (scores from keys,
//     softmax, ctx from enc8) -> ctx bf16 + attn row.  keys[b] on XCD b&7.
//   C (p>=4, 32 blk): h-cols [64x+16(p-4)..+16): gi 48 Wih-rows x 64 batches
//     MFMA from staged ctx; GRU local; h slice persists in LDS f32.
// 3 global store-slot barriers/step (64 posted arrivals, leader poll,
// 8-leaf-flag release).  Zero atomics; single writer per address.
// ============================================================================

typedef short s8v __attribute__((ext_vector_type(8)));
typedef float f4v __attribute__((ext_vector_type(4)));
typedef float f2v __attribute__((ext_vector_type(2)));
typedef unsigned long long u64;

// ws byte offsets
#define OFF_BAR    0u          // slots [0..63], leaf flags at uint 128+16*l
#define OFF_HBF    4096u       // [64][512] bf16 h broadcast
#define OFF_Q      69632u      // [64][512] f32 (q + ba)
#define OFF_GH     200704u     // [64][1536] f32 (gh + bhh)
#define OFF_CTX    593920u     // [64][512] bf16 normalized ctx
#define OFF_WCAT   659456u     // [2560][512] bf16 : Wa | Whh | Wout
#define OFF_WIH    3280896u    // [1536][512] bf16
#define OFF_KEYS   4853760u    // [64*256][512] bf16 : Ek = exp(2*(Ua.enc+bu))
#define OFF_ENC8   21630976u   // [64*256*512] fp8
#define MEMSET_BYTES 69632u    // bar + hbf

// d_out offsets (floats)
#define OUT_HFIN   8388608u
#define OUT_ATTN   8421376u

__device__ __forceinline__ unsigned short f2bf(float f) {
  union { float f; unsigned u; } a; a.f = f;
  unsigned r = a.u + 0x7fffu + ((a.u >> 16) & 1u);
  return (unsigned short)(r >> 16);
}
__device__ __forceinline__ float bf2f(unsigned short h) {
  union { unsigned u; float f; } a; a.u = (unsigned)h << 16; return a.f;
}
__device__ __forceinline__ float cload(const float* p) {
  return __hip_atomic_load(p, __ATOMIC_RELAXED, __HIP_MEMORY_SCOPE_AGENT);
}
__device__ __forceinline__ void cstore(float* p, float v) {
  __hip_atomic_store(p, v, __ATOMIC_RELAXED, __HIP_MEMORY_SCOPE_AGENT);
}
__device__ __forceinline__ void cstoreu(unsigned* p, unsigned v) {
  __hip_atomic_store(p, v, __ATOMIC_RELAXED, __HIP_MEMORY_SCOPE_AGENT);
}
__device__ __forceinline__ u64 cload64(const u64* p) {
  return __hip_atomic_load(p, __ATOMIC_RELAXED, __HIP_MEMORY_SCOPE_AGENT);
}
__device__ __forceinline__ float sigm(float x) {
  return __builtin_amdgcn_rcpf(1.f + __expf(-x));
}
__device__ __forceinline__ float tanh2(float x) {
  return 1.f - 2.f * __builtin_amdgcn_rcpf(1.f + __expf(x + x));
}
__device__ __forceinline__ f4v mfma16(s8v a, s8v b, f4v c) {
  return __builtin_amdgcn_mfma_f32_16x16x32_bf16(a, b, c, 0, 0, 0);
}

// 64-block store-slot barrier: posted arrivals, leader polls, leaf fanout.
__device__ __forceinline__ void gbar64(unsigned* bar, int bid, unsigned& gen) {
  asm volatile("s_waitcnt vmcnt(0) lgkmcnt(0)" ::: "memory");
  __syncthreads();
  if (threadIdx.x == 0) {
    __atomic_signal_fence(__ATOMIC_SEQ_CST);
    gen++;
    __hip_atomic_store(bar + bid, gen, __ATOMIC_RELAXED, __HIP_MEMORY_SCOPE_AGENT);
    if (bid == 0) {
      for (;;) {
        unsigned mn = 0xffffffffu;
#pragma unroll
        for (int i = 0; i < 64; ++i) {
          unsigned v = __hip_atomic_load(bar + i, __ATOMIC_RELAXED,
                                         __HIP_MEMORY_SCOPE_AGENT);
          mn = (v < mn) ? v : mn;
        }
        if (mn >= gen) break;
        __builtin_amdgcn_s_sleep(0);
      }
#pragma unroll
      for (int l = 0; l < 8; ++l)
        __hip_atomic_store(bar + 128 + l * 16, gen, __ATOMIC_RELAXED,
                           __HIP_MEMORY_SCOPE_AGENT);
    } else {
      const int leaf = bid >> 3;
      while (__hip_atomic_load(bar + 128 + leaf * 16, __ATOMIC_RELAXED,
                               __HIP_MEMORY_SCOPE_AGENT) < gen)
        __builtin_amdgcn_s_sleep(1);
    }
    __atomic_signal_fence(__ATOMIC_SEQ_CST);
  }
  __syncthreads();
}

// ---------------------------------------------------------------------------
// prep: wcat=[Wa|Whh|Wout] bf16, wih bf16, enc8 fp8
// ---------------------------------------------------------------------------
__global__ void __launch_bounds__(256) prep_kernel(
    const float* __restrict__ Wa, const float* __restrict__ Whh,
    const float* __restrict__ Wout, const float* __restrict__ Wih,
    const float* __restrict__ enc,
    unsigned short* __restrict__ wcat, unsigned short* __restrict__ wihb,
    unsigned char* __restrict__ enc8) {
  const size_t gid = (size_t)blockIdx.x * 256 + threadIdx.x;
  const size_t stride = (size_t)gridDim.x * 256;
  for (size_t i = gid; i < 2097152u; i += stride) {
    float v; unsigned short* d;
    if (i < 262144u)       { v = Wa[i];              d = wcat + i; }
    else if (i < 1048576u) { v = Whh[i - 262144u];   d = wcat + i; }
    else if (i < 1310720u) { v = Wout[i - 1048576u]; d = wcat + i; }
    else                   { v = Wih[i - 1310720u];  d = wihb + (i - 1310720u); }
    *d = f2bf(v);
  }
  for (size_t j = gid; j < 4194304u; j += stride) {
    float2 e = ((const float2*)enc)[j];
    int pk = __builtin_amdgcn_cvt_pk_fp8_f32(e.x, e.y, 0, false);
    ((unsigned short*)enc8)[j] = (unsigned short)(pk & 0xffff);
  }
}

// ---------------------------------------------------------------------------
// keys[b*256+s][h] = exp(2*(enc[b,s]·Ua[h] + bu[h]))  (bf16)
// ---------------------------------------------------------------------------
__global__ void __launch_bounds__(256) keys_kernel(
    const float* __restrict__ enc, const float* __restrict__ Ua,
    const float* __restrict__ bu, unsigned short* __restrict__ keysb) {
  const int tid = threadIdx.x;
  const int w = tid >> 6, lane = tid & 63, ln = lane & 15, kq = lane >> 4;
  const int mb = blockIdx.x >> 3, nb = blockIdx.x & 7;
  const int mrow = mb * 64 + w * 16 + ln;
  f4v acc[4] = {{0,0,0,0},{0,0,0,0},{0,0,0,0},{0,0,0,0}};
  for (int ks = 0; ks < 16; ++ks) {
    const float* ap = enc + (size_t)mrow * 512 + ks * 32 + kq * 8;
    s8v af;
#pragma unroll
    for (int j = 0; j < 8; ++j) af[j] = (short)f2bf(ap[j]);
#pragma unroll
    for (int nt = 0; nt < 4; ++nt) {
      int n = nb * 64 + nt * 16 + ln;
      const float* up = Ua + (size_t)n * 512 + ks * 32 + kq * 8;
      s8v bf;
#pragma unroll
      for (int j = 0; j < 8; ++j) bf[j] = (short)f2bf(up[j]);
      acc[nt] = mfma16(af, bf, acc[nt]);
    }
  }
#pragma unroll
  for (int nt = 0; nt < 4; ++nt) {
    int n = nb * 64 + nt * 16 + ln;
    float bias = bu[n];
#pragma unroll
    for (int r = 0; r < 4; ++r) {
      int gm = mb * 64 + w * 16 + kq * 4 + r;
      keysb[(size_t)gm * 512 + n] = f2bf(__expf(2.f * (acc[nt][r] + bias)));
    }
  }
}

// ---------------------------------------------------------------------------
// persistent decoder: 64 blocks x 512 threads
// ---------------------------------------------------------------------------
__global__ void __launch_bounds__(512, 1) decoder_kernel(
    const float* __restrict__ ba_, const float* __restrict__ va_,
    const float* __restrict__ bih_, const float* __restrict__ bhh_,
    const float* __restrict__ bout_,
    const unsigned short* __restrict__ wcat, const unsigned short* __restrict__ wihb,
    const unsigned short* __restrict__ keysb, const unsigned char* __restrict__ enc8,
    unsigned* __restrict__ bar, unsigned short* __restrict__ hbf,
    float* __restrict__ qst, float* __restrict__ ghst,
    unsigned short* __restrict__ ctxg, float* __restrict__ out) {
  const int bid = blockIdx.x, tid = threadIdx.x;
  const int w = tid >> 6, lane = tid & 63, ln = lane & 15, kq = lane >> 4;
  const int x = bid & 7, p = bid >> 3;
  const int b = bid;                             // phase-B batch

  float* logits = out;
  float* hfin   = out + OUT_HFIN;
  float* attn   = out + OUT_ATTN;

  // stageA: XOR-swizzled [64][512] bf16 (A: h rows; C: ctx rows — disjoint blocks)
  __shared__ unsigned short stageA[64 * 512];
  __shared__ float EqL[512];
  __shared__ float swL[256];
  __shared__ float ZpL[8];
  __shared__ float cpart[2][256][2];
  __shared__ float hL[64][16];                   // C: persistent h slice (f32)
  __shared__ float nacc[64 * 20];                // C: gate-n exchange

  unsigned gen = 0;

  // ---- loop invariants ---------------------------------------------------
  float vav[8]; float vasum;
  {
    float vs = 0.f;
#pragma unroll
    for (int jj = 0; jj < 8; ++jj) { vav[jj] = va_[lane * 8 + jj]; vs += vav[jj]; }
#pragma unroll
    for (int off = 32; off > 0; off >>= 1) vs += __shfl_xor(vs, off, 64);
    vasum = vs;
  }
  // C invariants
  const int col16 = x * 64 + (p - 4) * 16;       // valid when p>=4
  const int colC = (p >= 4) ? (col16 + ln) : ln;
  float bihv[3];
#pragma unroll
  for (int g = 0; g < 3; ++g) bihv[g] = bih_[g * 512 + colC];
  if (p >= 4) {
    for (int i = tid; i < 1024; i += 512) ((float*)hL)[i] = 0.f;
  }
  __syncthreads();

#pragma clang loop unroll(disable)
  for (int it = 0; it <= 256; ++it) {
    // ============ A: [q|gh|logits_{it-1}] = h @ Wcat^T (p<4) ===============
    if (p < 4) {
      {
        const u64* hb = (const u64*)hbf;
        u64 tv[16];
#pragma unroll
        for (int k = 0; k < 16; ++k) tv[k] = cload64(hb + k * 512 + tid);
#pragma unroll
        for (int k = 0; k < 16; ++k) {
          int i = k * 512 + tid;
          int row = i >> 7, c = i & 127;
          int g2 = c >> 1, half = c & 1;
          ((u64*)stageA)[row * 128 + (((g2 ^ (row & 7)) << 1) | half)] = tv[k];
        }
      }
      __syncthreads();
#pragma clang loop unroll(disable)
      for (int pi = w; pi < 20; pi += 8) {
        int j = pi >> 2, mt = pi & 3;
        int colg = (x * 20 + p * 5 + j) * 16 + ln;
        int rg2 = (colg < 512) ? 0 : (colg < 2048) ? 1 : 2;
        if ((rg2 == 2 && it == 0) || (rg2 != 2 && it == 256)) continue;
        const s8v* wp = (const s8v*)(wcat + (size_t)colg * 512);
        f4v acc = {0.f, 0.f, 0.f, 0.f};
#pragma unroll
        for (int ks = 0; ks < 16; ++ks) {
          int row = mt * 16 + ln;
          s8v af = ((const s8v*)stageA)[row * 64 + ((ks * 4 + kq) ^ (row & 7))];
          acc = mfma16(af, wp[ks * 4 + kq], acc);
        }
        float bias = (rg2 == 0) ? ba_[colg]
                   : (rg2 == 1) ? bhh_[colg - 512] : bout_[colg - 2048];
#pragma unroll
        for (int r = 0; r < 4; ++r) {
          int bb = mt * 16 + kq * 4 + r;
          float v = acc[r] + bias;
          if (rg2 == 0)
            cstore(qst + (size_t)bb * 512 + colg, v);
          else if (rg2 == 1)
            cstore(ghst + (size_t)bb * 1536 + (colg - 512), v);
          else
            cstore(logits + (size_t)(it - 1) * 32768 + (size_t)bb * 512 + (colg - 2048), v);
        }
      }
      __syncthreads();          // protect stageA until writes drained (gbar waits anyway)
    }
    gbar64(bar, bid, gen);
    if (it == 256) break;

    // ============ B: attention for batch b (all 64 blocks) =================
    {
      float qv = cload(qst + (size_t)b * 512 + tid);
      EqL[tid] = __expf(2.f * qv);
    }
    __syncthreads();
    {
      float eq[8];
#pragma unroll
      for (int jj = 0; jj < 8; ++jj) eq[jj] = EqL[lane * 8 + jj];
      const unsigned short* kbase =
          keysb + ((size_t)b * 256 + w * 32) * 512 + lane * 8;
      float zacc = 0.f;
#pragma clang loop unroll(disable)
      for (int i0 = 0; i0 < 32; i0 += 8) {
        s8v kv[8];
#pragma unroll
        for (int i = 0; i < 8; ++i)
          kv[i] = *(const s8v*)(kbase + (size_t)(i0 + i) * 512);
#pragma unroll
        for (int i = 0; i < 8; ++i) {
          float a2 = 0.f;
#pragma unroll
          for (int jj = 0; jj < 8; ++jj) {
            float P = eq[jj] * bf2f((unsigned short)kv[i][jj]);
            a2 += vav[jj] * __builtin_amdgcn_rcpf(1.f + P);
          }
#pragma unroll
          for (int off = 32; off > 0; off >>= 1) a2 += __shfl_xor(a2, off, 64);
          float wt = __expf(vasum - 2.f * a2);
          if (lane == 0) swL[w * 32 + i0 + i] = wt;
          zacc += wt;
        }
      }
      if (lane == 0) ZpL[w] = zacc;
    }
    __syncthreads();
    float Z = 0.f;
#pragma unroll
    for (int l = 0; l < 8; ++l) Z += ZpL[l];
    float invZ = __builtin_amdgcn_rcpf(Z);
    {
      const int hp = tid & 255, sh = tid >> 8;
      const int s0 = sh * 128;
      const unsigned char* ep = enc8 + ((size_t)b * 256 + s0) * 512 + hp * 2;
      float c0 = 0.f, c1 = 0.f;
#pragma unroll 8
      for (int i = 0; i < 128; ++i) {
        float wt = swL[s0 + i];
        unsigned short v8 = *(const unsigned short*)(ep + (size_t)i * 512);
        f2v ef = __builtin_amdgcn_cvt_pk_f32_fp8((int)v8, false);
        c0 += wt * ef[0]; c1 += wt * ef[1];
      }
      cpart[sh][hp][0] = c0; cpart[sh][hp][1] = c1;
    }
    __syncthreads();
    if (tid < 256) {
      float cc0 = (cpart[0][tid][0] + cpart[1][tid][0]) * invZ;
      float cc1 = (cpart[0][tid][1] + cpart[1][tid][1]) * invZ;
      unsigned pk = (unsigned)f2bf(cc0) | ((unsigned)f2bf(cc1) << 16);
      cstoreu((unsigned*)ctxg + (size_t)b * 256 + tid, pk);
      attn[(size_t)b * 65536 + (size_t)it * 256 + tid] = swL[tid] * invZ;
    }
    gbar64(bar, bid, gen);

    // ============ C: gi + GRU for h-cols [col16..col16+16) (p>=4) ==========
    if (p >= 4) {
      {
        const u64* cb = (const u64*)ctxg;
        u64 tv[16];
#pragma unroll
        for (int k = 0; k < 16; ++k) tv[k] = cload64(cb + k * 512 + tid);
#pragma unroll
        for (int k = 0; k < 16; ++k) {
          int i = k * 512 + tid;
          int row = i >> 7, c = i & 127;
          int g2 = c >> 1, half = c & 1;
          ((u64*)stageA)[row * 128 + (((g2 ^ (row & 7)) << 1) | half)] = tv[k];
        }
      }
      __syncthreads();
      const int mt = w & 3;
      f4v aR = {0,0,0,0}, aZ = {0,0,0,0};
      if (w < 4) {
        const s8v* wr = (const s8v*)(wihb + (size_t)colC * 512);
        const s8v* wz = (const s8v*)(wihb + (size_t)(512 + colC) * 512);
#pragma unroll
        for (int ks = 0; ks < 16; ++ks) {
          int row = mt * 16 + ln;
          s8v af = ((const s8v*)stageA)[row * 64 + ((ks * 4 + kq) ^ (row & 7))];
          aR = mfma16(af, wr[ks * 4 + kq], aR);
          aZ = mfma16(af, wz[ks * 4 + kq], aZ);
        }
      } else {
        f4v aN = {0,0,0,0};
        const s8v* wn = (const s8v*)(wihb + (size_t)(1024 + colC) * 512);
#pragma unroll
        for (int ks = 0; ks < 16; ++ks) {
          int row = mt * 16 + ln;
          s8v af = ((const s8v*)stageA)[row * 64 + ((ks * 4 + kq) ^ (row & 7))];
          aN = mfma16(af, wn[ks * 4 + kq], aN);
        }
#pragma unroll
        for (int r = 0; r < 4; ++r)
          nacc[(mt * 16 + kq * 4 + r) * 20 + ln] = aN[r];
      }
      __syncthreads();
      if (w < 4) {
        float tgh[12];
#pragma unroll
        for (int r = 0; r < 4; ++r)
#pragma unroll
          for (int g = 0; g < 3; ++g)
            tgh[r * 3 + g] = cload(ghst + (size_t)(mt * 16 + kq * 4 + r) * 1536 +
                                   g * 512 + colC);
#pragma unroll
        for (int r = 0; r < 4; ++r) {
          int bb = mt * 16 + kq * 4 + r;
          float rr = sigm(aR[r] + bihv[0] + tgh[r * 3 + 0]);
          float zz = sigm(aZ[r] + bihv[1] + tgh[r * 3 + 1]);
          float nn = tanh2(nacc[bb * 20 + ln] + bihv[2] + rr * tgh[r * 3 + 2]);
          float ho = hL[bb][ln];
          float hn = (1.f - zz) * nn + zz * ho;
          hL[bb][ln] = hn;
          unsigned hb16 = (unsigned)f2bf(hn);
          unsigned other = (unsigned)__shfl_xor((int)hb16, 1, 64);
          if (!(ln & 1))
            cstoreu((unsigned*)hbf + (size_t)bb * 256 + (colC >> 1),
                    hb16 | (other << 16));
          if (it == 255) hfin[(size_t)bb * 512 + colC] = hn;
        }
      }
      __syncthreads();          // protect nacc/stageA for next iteration
    }
    gbar64(bar, bid, gen);
  }

  // -------- finale: log_softmax over this block's 256 rows -----------------
#pragma clang loop unroll(disable)
  for (int i = 0; i < 32; ++i) {
    int row = bid * 256 + w * 32 + i;
    const u64* xr64 = (const u64*)(logits + (size_t)row * 512) + lane * 4;
    u64 t4[4];
#pragma unroll
    for (int jj = 0; jj < 4; ++jj) t4[jj] = cload64(xr64 + jj);
    union { u64 u[4]; float f[8]; } xu;
#pragma unroll
    for (int jj = 0; jj < 4; ++jj) xu.u[jj] = t4[jj];
    float mx = xu.f[0];
#pragma unroll
    for (int jj = 1; jj < 8; ++jj) mx = fmaxf(mx, xu.f[jj]);
#pragma unroll
    for (int off = 32; off > 0; off >>= 1) mx = fmaxf(mx, __shfl_xor(mx, off, 64));
    float sm = 0.f;
#pragma unroll
    for (int jj = 0; jj < 8; ++jj) sm += __expf(xu.f[jj] - mx);
#pragma unroll
    for (int off = 32; off > 0; off >>= 1) sm += __shfl_xor(sm, off, 64);
    float lse = mx + __logf(sm);
    float* xw = logits + (size_t)row * 512 + lane * 8;
    f4v o0, o1;
#pragma unroll
    for (int jj = 0; jj < 4; ++jj) { o0[jj] = xu.f[jj] - lse; o1[jj] = xu.f[4 + jj] - lse; }
    ((f4v*)xw)[0] = o0;
    ((f4v*)xw)[1] = o1;
  }
}

// ---------------------------------------------------------------------------
extern "C" void kernel_launch(void* const* d_in, const int* in_sizes, int n_in,
                              void* d_out, int out_size, void* d_ws, size_t ws_size,
                              hipStream_t stream) {
  const float* enc  = (const float*)d_in[0];
  const float* Wa   = (const float*)d_in[1];
  const float* ba   = (const float*)d_in[2];
  const float* Ua   = (const float*)d_in[3];
  const float* bu   = (const float*)d_in[4];
  const float* Va   = (const float*)d_in[5];
  // d_in[6] = bv : softmax-invariant, unused
  const float* Wih  = (const float*)d_in[7];
  const float* bih  = (const float*)d_in[8];
  const float* Whh  = (const float*)d_in[9];
  const float* bhh  = (const float*)d_in[10];
  const float* Wout = (const float*)d_in[11];
  const float* bout = (const float*)d_in[12];
  (void)in_sizes; (void)n_in; (void)out_size; (void)ws_size;

  char* ws = (char*)d_ws;
  unsigned*       bar   = (unsigned*)(ws + OFF_BAR);
  unsigned short* hbf   = (unsigned short*)(ws + OFF_HBF);
  float*          qst   = (float*)(ws + OFF_Q);
  float*          ghst  = (float*)(ws + OFF_GH);
  unsigned short* ctxg  = (unsigned short*)(ws + OFF_CTX);
  unsigned short* wcat  = (unsigned short*)(ws + OFF_WCAT);
  unsigned short* wihb  = (unsigned short*)(ws + OFF_WIH);
  unsigned short* keysb = (unsigned short*)(ws + OFF_KEYS);
  unsigned char*  enc8  = (unsigned char*)(ws + OFF_ENC8);

  hipMemsetAsync(d_ws, 0, MEMSET_BYTES, stream);       // bar + hbf (h0 = 0)
  prep_kernel<<<1024, 256, 0, stream>>>(Wa, Whh, Wout, Wih, enc,
                                        wcat, wihb, enc8);
  keys_kernel<<<2048, 256, 0, stream>>>(enc, Ua, bu, keysb);
  decoder_kernel<<<64, 512, 0, stream>>>(ba, Va, bih, bhh, bout,
                                         wcat, wihb, keysb, enc8,
                                         bar, hbf, qst, ghst, ctxg,
                                         (float*)d_out);
}